// Round 1
// baseline (2711.430 us; speedup 1.0000x reference)
//
#include <hip/hip_runtime.h>
#include <cstdint>
#include <cstddef>

// SimpleRNN: B=4096, K=512, U=3, P=5, LIFT=32, HID=128, NSUB=10
// Design: 256 workgroups x 256 threads; each wg owns 16 batch rows for all 512 steps.
// GRU gates via f16 MFMA 16x16x32, weights held as register-resident B-fragments
// (each wave owns r-chunks {2w,2w+1} plus matching z,n chunks). h carried fp32 in LDS,
// f16 copy for MFMA A-fragments. RK4 on lanes 0..15 of wave 0 (serial, round-0 simple).

#define KTOT 512
#define BB   16

typedef _Float16 half8 __attribute__((ext_vector_type(8)));
typedef float    f32x4 __attribute__((ext_vector_type(4)));

struct __align__(16) Smem {
  float    h32 [BB][129];   // fp32 hidden state (padded: conflict-free)
  _Float16 hf16[BB][136];   // f16 hidden (A-frag source, padded rows = 272B)
  _Float16 xf16[BB][40];    // f16 lift output (padded rows = 80B)
  _Float16 WhF [4*64*8];    // head B-fragments [kstep][lane][8]
  float    Wl  [32][8];
  float    bl  [32];
  float    brz [256];       // b_ih + b_hh for r,z gates
  float    bnx [128];       // b_ih for n gate
  float    bnh [128];       // b_hh for n gate
  float    bhv [16];
  float    jmp [16];        // u_to_y_jump (3x5), row-major
  float    theta[BB][16];
  float    yst [BB][8];
  float    ust [BB][4];
};

__device__ __forceinline__ float sigm(float x)     { return 1.f / (1.f + __expf(-x)); }
__device__ __forceinline__ float tanhfast(float x) { return 1.f - 2.f / (1.f + __expf(2.f * x)); }

__global__ __launch_bounds__(256, 1) void rnn_scan_kernel(
    const float* __restrict__ y0,    const float* __restrict__ u_seq,
    const float* __restrict__ dt_sq, const float* __restrict__ Wl,
    const float* __restrict__ bl,    const float* __restrict__ W_ih,
    const float* __restrict__ b_ih,  const float* __restrict__ W_hh,
    const float* __restrict__ b_hh,  const float* __restrict__ Wh,
    const float* __restrict__ bh,    const float* __restrict__ jmp,
    float* __restrict__ y_out, float* __restrict__ th_out)
{
  __shared__ Smem sm;
  const int t   = threadIdx.x;
  const int w   = t >> 6;   // wave id 0..3
  const int l   = t & 63;   // lane
  const int n16 = l & 15;   // MFMA col (N) / A-frag row (M)
  const int q   = l >> 4;   // MFMA quad
  const int B0  = blockIdx.x * BB;

  // ---------------- one-time init ----------------
  for (int i = t; i < 32*8; i += 256) ((float*)sm.Wl)[i] = Wl[i];
  if (t < 32)  sm.bl[t] = bl[t];
  sm.brz[t] = b_ih[t] + b_hh[t];                       // t in [0,256)
  if (t < 128) { sm.bnx[t] = b_ih[256+t]; sm.bnh[t] = b_hh[256+t]; }
  if (t < 16)  sm.bhv[t] = (t < 13) ? bh[t] : 0.f;
  if (t < 16)  sm.jmp[t] = (t < 15) ? jmp[t] : 0.f;
  { // head B-fragments: B[k][n] = Wh[n][k] (n<13 else 0), frag-linear layout
    const int tt = t >> 6, ll = t & 63;
    const int nn = ll & 15, qq = ll >> 4;
    #pragma unroll
    for (int i = 0; i < 8; i++) {
      const int kk = tt*32 + qq*8 + i;
      sm.WhF[(tt*64 + ll)*8 + i] = (nn < 13) ? (_Float16)Wh[nn*128 + kk] : (_Float16)0.f;
    }
  }
  for (int i = t; i < BB*129; i += 256) ((float*)sm.h32)[i] = 0.f;
  for (int i = t; i < BB*136; i += 256) ((_Float16*)sm.hf16)[i] = (_Float16)0.f;
  if (t < 128) { const int b = t >> 3, i = t & 7;
    sm.yst[b][i] = (i < 5) ? (y0[(size_t)(B0+b)*5 + i] + 0.01f) : 0.f; }

  // Register-resident weight fragments.
  // B-frag layout: lane holds B[k][n] with n = l&15, k = q*8 + i  (K chunk of 32).
  // gh: B = W_hh^T  -> value = W_hh[j][k];  gx: B = W_ih^T -> value = W_ih[j][k].
  half8 wihR[2], wihZ[2], wihN[2], whhR[2][4], whhZ[2][4], whhN[2][4];
  #pragma unroll
  for (int p = 0; p < 2; p++) {
    const int jR = (2*w + p)*16 + n16;       // gate row in [0,128)
    const int jZ = jR + 128, jN = jR + 256;
    #pragma unroll
    for (int i = 0; i < 8; i++) {
      const int kk = q*8 + i;
      wihR[p][i] = (_Float16)W_ih[jR*32 + kk];
      wihZ[p][i] = (_Float16)W_ih[jZ*32 + kk];
      wihN[p][i] = (_Float16)W_ih[jN*32 + kk];
    }
    #pragma unroll
    for (int ks = 0; ks < 4; ks++) {
      #pragma unroll
      for (int i = 0; i < 8; i++) {
        const int kk = ks*32 + q*8 + i;
        whhR[p][ks][i] = (_Float16)W_hh[jR*128 + kk];
        whhZ[p][ks][i] = (_Float16)W_hh[jZ*128 + kk];
        whhN[p][ks][i] = (_Float16)W_hh[jN*128 + kk];
      }
    }
  }
  half8 hfrag[4];
  #pragma unroll
  for (int ks = 0; ks < 4; ks++)
    #pragma unroll
    for (int i = 0; i < 8; i++) hfrag[ks][i] = (_Float16)0.f;

  __syncthreads();

  const f32x4 zero4 = {0.f, 0.f, 0.f, 0.f};

  #pragma unroll 1
  for (int k = 0; k < KTOT; k++) {
    // ---- phase A: lift x = silu([u,y_prev] @ Wl^T + bl) ----
    {
      const int b = t >> 4, o = (t & 15) * 2;
      const float* up = u_seq + ((size_t)(B0 + b)*KTOT + k)*3;
      const float u0 = up[0], u1 = up[1], u2 = up[2];
      if ((t & 15) == 0) { sm.ust[b][0]=u0; sm.ust[b][1]=u1; sm.ust[b][2]=u2; }
      const float ya = sm.yst[b][0], yb = sm.yst[b][1], yc = sm.yst[b][2],
                  yd = sm.yst[b][3], ye = sm.yst[b][4];
      #pragma unroll
      for (int oo = o; oo < o + 2; oo++) {
        const float a = sm.bl[oo]
          + u0*sm.Wl[oo][0] + u1*sm.Wl[oo][1] + u2*sm.Wl[oo][2]
          + ya*sm.Wl[oo][3] + yb*sm.Wl[oo][4] + yc*sm.Wl[oo][5]
          + yd*sm.Wl[oo][6] + ye*sm.Wl[oo][7];
        sm.xf16[b][oo] = (_Float16)(a * sigm(a));
      }
    }
    __syncthreads();

    // ---- phase B: GRU gates via MFMA, h update (no cross-lane exchange) ----
    {
      const half8 xf = *(const half8*)&sm.xf16[n16][q*8];
      f32x4 accR[2], accZ[2], accXN[2], accHN[2];
      #pragma unroll
      for (int p = 0; p < 2; p++) {
        accR[p]  = __builtin_amdgcn_mfma_f32_16x16x32_f16(xf, wihR[p], zero4, 0,0,0);
        accZ[p]  = __builtin_amdgcn_mfma_f32_16x16x32_f16(xf, wihZ[p], zero4, 0,0,0);
        accXN[p] = __builtin_amdgcn_mfma_f32_16x16x32_f16(xf, wihN[p], zero4, 0,0,0);
        accHN[p] = zero4;
        #pragma unroll
        for (int ks = 0; ks < 4; ks++) {
          accR[p]  = __builtin_amdgcn_mfma_f32_16x16x32_f16(hfrag[ks], whhR[p][ks], accR[p], 0,0,0);
          accZ[p]  = __builtin_amdgcn_mfma_f32_16x16x32_f16(hfrag[ks], whhZ[p][ks], accZ[p], 0,0,0);
          accHN[p] = __builtin_amdgcn_mfma_f32_16x16x32_f16(hfrag[ks], whhN[p][ks], accHN[p], 0,0,0);
        }
      }
      // C/D layout: col(N=gate) = l&15, row(M=batch) = q*4 + reg  [m89-verified]
      #pragma unroll
      for (int p = 0; p < 2; p++) {
        const int jl = 32*w + 16*p + n16;          // gate index in [0,128)
        const float br = sm.brz[jl], bz = sm.brz[128 + jl];
        const float bx = sm.bnx[jl], bn = sm.bnh[jl];
        #pragma unroll
        for (int rg = 0; rg < 4; rg++) {
          const int brow = q*4 + rg;
          const float r  = sigm(accR[p][rg] + br);
          const float z  = sigm(accZ[p][rg] + bz);
          const float nn = tanhfast(accXN[p][rg] + bx + r*(accHN[p][rg] + bn));
          const float ho = sm.h32[brow][jl];
          const float hn = nn + z*(ho - nn);       // (1-z)*n + z*h
          sm.h32[brow][jl]  = hn;
          sm.hf16[brow][jl] = (_Float16)hn;
        }
      }
    }
    __syncthreads();

    // ---- phase C: reload h fragments (reused for head now + gh next step); head on wave 0 ----
    #pragma unroll
    for (int ks = 0; ks < 4; ks++)
      hfrag[ks] = *(const half8*)&sm.hf16[n16][ks*32 + q*8];
    if (w == 0) {
      f32x4 accH = zero4;
      #pragma unroll
      for (int ks = 0; ks < 4; ks++) {
        const half8 wf = *(const half8*)&sm.WhF[(ks*64 + l)*8];
        accH = __builtin_amdgcn_mfma_f32_16x16x32_f16(hfrag[ks], wf, accH, 0,0,0);
      }
      const float bb = sm.bhv[n16];
      #pragma unroll
      for (int rg = 0; rg < 4; rg++) {
        const int b = q*4 + rg;
        const float sg = sigm(accH[rg] + bb);
        const float th = (n16 < 8) ? (0.01f + 2.99f*sg) : (0.3f*sg);
        if (n16 < 13) {
          sm.theta[b][n16] = th;
          th_out[((size_t)(B0 + b)*KTOT + k)*13 + n16] = th;
        }
      }
    }
    __syncthreads();

    // ---- phase D: bolus jump + 10x RK4 (lanes 0..15) ----
    if (t < BB) {
      const int b = t;
      const float kf1 = sm.theta[b][0], kf2 = sm.theta[b][1], kf3 = sm.theta[b][2], kf4 = sm.theta[b][3];
      const float kr1 = sm.theta[b][4], kr2 = sm.theta[b][5], kr3 = sm.theta[b][6], kr4 = sm.theta[b][7];
      const float kj1 = sm.theta[b][8], kj2 = sm.theta[b][9], kj3 = sm.theta[b][10],
                  kj4 = sm.theta[b][11], kj5 = sm.theta[b][12];
      const float u0 = sm.ust[b][0], u1 = sm.ust[b][1], u2 = sm.ust[b][2];
      float y[5];
      #pragma unroll
      for (int i = 0; i < 5; i++)
        y[i] = sm.yst[b][i] + u0*sm.jmp[i] + u1*sm.jmp[5+i] + u2*sm.jmp[10+i];
      const float dt = dt_sq[(size_t)(B0 + b)*KTOT + k];
      const float h = dt * 0.1f, hh = 0.5f*h, h6 = h*(1.f/6.f);
      const float s1 = kr1 + kf2, s2 = kr2 + kf3, s3 = kr3 + kf4;
      #define RHS(Y, DY) \
        DY[0] = kj1 + kr1*Y[1] - kf1*Y[0]; \
        DY[1] = kj2 + kf1*Y[0] - s1*Y[1] + kr2*Y[2]; \
        DY[2] = kj3 + kf2*Y[1] - s2*Y[2] + kr3*Y[3]; \
        DY[3] = kj4 + kf3*Y[2] - s3*Y[3] + kr4*Y[4]; \
        DY[4] = kj5 + kf4*Y[3] - kr4*Y[4];
      #pragma unroll 1
      for (int ss = 0; ss < 10; ss++) {
        float k1[5], k2[5], k3[5], k4[5], tp[5];
        RHS(y, k1);
        #pragma unroll
        for (int i = 0; i < 5; i++) tp[i] = y[i] + hh*k1[i];
        RHS(tp, k2);
        #pragma unroll
        for (int i = 0; i < 5; i++) tp[i] = y[i] + hh*k2[i];
        RHS(tp, k3);
        #pragma unroll
        for (int i = 0; i < 5; i++) tp[i] = y[i] + h*k3[i];
        RHS(tp, k4);
        #pragma unroll
        for (int i = 0; i < 5; i++)
          y[i] = fmaxf(y[i] + h6*(k1[i] + 2.f*(k2[i] + k3[i]) + k4[i]), 0.f);
      }
      #undef RHS
      #pragma unroll
      for (int i = 0; i < 5; i++) sm.yst[b][i] = y[i];
      float* yo = y_out + ((size_t)(B0 + b)*KTOT + k)*5;
      #pragma unroll
      for (int i = 0; i < 5; i++) yo[i] = y[i];
    }
    __syncthreads();
  }
}

extern "C" void kernel_launch(void* const* d_in, const int* in_sizes, int n_in,
                              void* d_out, int out_size, void* d_ws, size_t ws_size,
                              hipStream_t stream) {
  const float* y0     = (const float*)d_in[0];
  const float* u_seq  = (const float*)d_in[1];
  const float* dt_sq  = (const float*)d_in[2];
  const float* Wl     = (const float*)d_in[3];
  const float* bl     = (const float*)d_in[4];
  const float* W_ih   = (const float*)d_in[5];
  const float* b_ih   = (const float*)d_in[6];
  const float* W_hh   = (const float*)d_in[7];
  const float* b_hh   = (const float*)d_in[8];
  const float* Wh     = (const float*)d_in[9];
  const float* bh     = (const float*)d_in[10];
  const float* jmp    = (const float*)d_in[11];
  float* y_out  = (float*)d_out;
  float* th_out = y_out + (size_t)4096 * KTOT * 5;   // y_out (B,K,5) then theta (B,K,13)
  rnn_scan_kernel<<<256, 256, 0, stream>>>(
      y0, u_seq, dt_sq, Wl, bl, W_ih, b_ih, W_hh, b_hh, Wh, bh, jmp, y_out, th_out);
}

// Round 2
// 1900.340 us; speedup vs baseline: 1.4268x; 1.4268x over previous
//
#include <hip/hip_runtime.h>
#include <cstdint>
#include <cstddef>

// SimpleRNN: B=4096, K=512, U=3, P=5, LIFT=32, HID=128, NSUB=10
// Round 2: 2-barrier step structure.
//   Phase G  (all waves): per-lane redundant lift -> gx+gh MFMA -> activations.
//            h held in registers (hreg); f16 copy -> LDS for next A-frags.
//            Global stores of step k-1 outputs issued HERE (drain overlaps phase).
//   Phase CD (wave0): head MFMA -> theta -> LDS transpose -> RK4 on 64 lanes
//            (16 batches x 4 states, y4 on lane3, quad_perm DPP neighbor xchg).
//            wave1/wave2: prefetch u(k+1), dt(k+1) into double-buffered LDS.

#define KTOT 512
#define BB   16

typedef _Float16 half8 __attribute__((ext_vector_type(8)));
typedef float    f32x4 __attribute__((ext_vector_type(4)));

struct __align__(16) Smem {
  _Float16 hf16[BB][136];   // f16 hidden (A-frag source)
  float Wlt[8][32];         // lift weight, transposed (bank-friendly broadcast)
  float bl[32];
  float brz[256];           // b_ih + b_hh for r,z
  float bnx[128];           // b_ih n-gate
  float bnh[128];           // b_hh n-gate
  float bhv[16];
  float theta[BB][14];
  float yst[BB][8];
  float ust[2][BB][4];      // double-buffered u
  float dtst[2][BB];        // double-buffered dt
};

__device__ __forceinline__ float sigm(float x)     { return 1.f / (1.f + __expf(-x)); }
__device__ __forceinline__ float tanhfast(float x) { return 1.f - 2.f / (1.f + __expf(2.f * x)); }

template<int CTRL>
__device__ __forceinline__ float dppf(float x) {
  return __int_as_float(__builtin_amdgcn_mov_dpp(__float_as_int(x), CTRL, 0xf, 0xf, true));
}
#define QP_PLUS  0x39   // quad_perm [1,2,3,0]: lane s <- y_{(s+1)&3}
#define QP_MINUS 0x93   // quad_perm [3,0,1,2]: lane s <- y_{(s-1)&3}

__global__ __launch_bounds__(256, 1) void rnn_scan_kernel(
    const float* __restrict__ y0,    const float* __restrict__ u_seq,
    const float* __restrict__ dt_sq, const float* __restrict__ Wl,
    const float* __restrict__ bl,    const float* __restrict__ W_ih,
    const float* __restrict__ b_ih,  const float* __restrict__ W_hh,
    const float* __restrict__ b_hh,  const float* __restrict__ Wh,
    const float* __restrict__ bh,    const float* __restrict__ jmp,
    float* __restrict__ y_out, float* __restrict__ th_out)
{
  __shared__ Smem sm;
  const int t   = threadIdx.x;
  const int w   = t >> 6;
  const int l   = t & 63;
  const int n16 = l & 15;
  const int q   = l >> 4;
  const int B0  = blockIdx.x * BB;

  // ---------------- one-time init ----------------
  for (int i = t; i < 32*8; i += 256) { const int oo = i >> 3, c = i & 7;
    sm.Wlt[c][oo] = Wl[i]; }
  if (t < 32)  sm.bl[t] = bl[t];
  sm.brz[t] = b_ih[t] + b_hh[t];
  if (t < 128) { sm.bnx[t] = b_ih[256+t]; sm.bnh[t] = b_hh[256+t]; }
  if (t < 16)  sm.bhv[t] = (t < 13) ? bh[t] : 0.f;
  if (t < 128) { const int b = t >> 3, i = t & 7;
    sm.yst[b][i] = (i < 5) ? (y0[(size_t)(B0+b)*5 + i] + 0.01f) : 0.f; }
  // prefetch step-0 u/dt
  if (t < 48) { const int b = t/3, c = t - b*3;
    sm.ust[0][b][c] = u_seq[((size_t)(B0+b)*KTOT + 0)*3 + c]; }
  if (t >= 48 && t < 64) sm.dtst[0][t-48] = dt_sq[(size_t)(B0+(t-48))*KTOT + 0];

  // head B-frags in registers (used by wave0 only)
  half8 whf[4];
  #pragma unroll
  for (int ks = 0; ks < 4; ks++)
    #pragma unroll
    for (int i = 0; i < 8; i++) {
      const int kk = ks*32 + q*8 + i;
      whf[ks][i] = (n16 < 13) ? (_Float16)Wh[n16*128 + kk] : (_Float16)0.f;
    }

  // GRU weight fragments (B-layout: value = W[j][k], j = output gate, k in chunk)
  half8 wihR[2], wihZ[2], wihN[2], whhR[2][4], whhZ[2][4], whhN[2][4];
  #pragma unroll
  for (int p = 0; p < 2; p++) {
    const int jR = (2*w + p)*16 + n16;
    const int jZ = jR + 128, jN = jR + 256;
    #pragma unroll
    for (int i = 0; i < 8; i++) {
      const int kk = q*8 + i;
      wihR[p][i] = (_Float16)W_ih[jR*32 + kk];
      wihZ[p][i] = (_Float16)W_ih[jZ*32 + kk];
      wihN[p][i] = (_Float16)W_ih[jN*32 + kk];
    }
    #pragma unroll
    for (int ks = 0; ks < 4; ks++)
      #pragma unroll
      for (int i = 0; i < 8; i++) {
        const int kk = ks*32 + q*8 + i;
        whhR[p][ks][i] = (_Float16)W_hh[jR*128 + kk];
        whhZ[p][ks][i] = (_Float16)W_hh[jZ*128 + kk];
        whhN[p][ks][i] = (_Float16)W_hh[jN*128 + kk];
      }
  }

  // h state: registers + zeroed A-frags for step 0
  float hreg[2][4];
  #pragma unroll
  for (int p = 0; p < 2; p++)
    #pragma unroll
    for (int rg = 0; rg < 4; rg++) hreg[p][rg] = 0.f;
  half8 hfrag[4];
  #pragma unroll
  for (int ks = 0; ks < 4; ks++)
    #pragma unroll
    for (int i = 0; i < 8; i++) hfrag[ks][i] = (_Float16)0.f;

  // RK4 lane mapping (wave0): lane = b4*4 + s_, y4 lives on s_==3
  const int s_ = l & 3, b4 = l >> 2;
  const float jr0 = jmp[0*5 + s_], jr1 = jmp[1*5 + s_], jr2 = jmp[2*5 + s_];
  const float j40 = (s_==3) ? jmp[4]  : 0.f;
  const float j41 = (s_==3) ? jmp[9]  : 0.f;
  const float j42 = (s_==3) ? jmp[14] : 0.f;

  // output store mapping (stores issued in phase G for step k-1)
  const int yb = t/5, yi = t - yb*5;                 // valid for t<80
  float* yo_base = y_out + ((size_t)(B0 + (yb & 15))*KTOT)*5 + yi;
  const int ts = (t >= 48) ? (t - 48) : 0;           // exactly 208 threads t in [48,256)
  const int tb = ts/13, tn = ts - tb*13;
  float* th_base = th_out + ((size_t)(B0 + tb)*KTOT)*13 + tn;
  // u-prefetch mapping (wave1)
  const int upb = l/3, upc = l - upb*3;              // valid for l<48

  __syncthreads();

  const f32x4 zero4 = {0.f, 0.f, 0.f, 0.f};

  #pragma unroll 1
  for (int k = 0; k < KTOT; k++) {
    const int buf = k & 1;

    // ---- phase G ----
    // stores of step k-1 outputs (drain overlaps the whole phase)
    if (k > 0) {
      if (t < 80)  yo_base[(size_t)(k-1)*5]  = sm.yst[yb][yi];
      if (t >= 48) th_base[(size_t)(k-1)*13] = sm.theta[tb][tn];
    }
    // per-lane redundant lift -> A-frag (x[n16][q*8+i])
    const float u0 = sm.ust[buf][n16][0], u1 = sm.ust[buf][n16][1], u2 = sm.ust[buf][n16][2];
    const float ya = sm.yst[n16][0], yB = sm.yst[n16][1], yc = sm.yst[n16][2],
                yd = sm.yst[n16][3], ye = sm.yst[n16][4];
    half8 xf;
    #pragma unroll
    for (int i = 0; i < 8; i++) {
      const int oo = q*8 + i;
      const float a = sm.bl[oo]
        + u0*sm.Wlt[0][oo] + u1*sm.Wlt[1][oo] + u2*sm.Wlt[2][oo]
        + ya*sm.Wlt[3][oo] + yB*sm.Wlt[4][oo] + yc*sm.Wlt[5][oo]
        + yd*sm.Wlt[6][oo] + ye*sm.Wlt[7][oo];
      xf[i] = (_Float16)(a * sigm(a));
    }
    // gates
    f32x4 accR[2], accZ[2], accXN[2], accHN[2];
    #pragma unroll
    for (int p = 0; p < 2; p++) {
      accR[p]  = __builtin_amdgcn_mfma_f32_16x16x32_f16(xf, wihR[p], zero4, 0,0,0);
      accZ[p]  = __builtin_amdgcn_mfma_f32_16x16x32_f16(xf, wihZ[p], zero4, 0,0,0);
      accXN[p] = __builtin_amdgcn_mfma_f32_16x16x32_f16(xf, wihN[p], zero4, 0,0,0);
      accHN[p] = zero4;
      #pragma unroll
      for (int ks = 0; ks < 4; ks++) {
        accR[p]  = __builtin_amdgcn_mfma_f32_16x16x32_f16(hfrag[ks], whhR[p][ks], accR[p], 0,0,0);
        accZ[p]  = __builtin_amdgcn_mfma_f32_16x16x32_f16(hfrag[ks], whhZ[p][ks], accZ[p], 0,0,0);
        accHN[p] = __builtin_amdgcn_mfma_f32_16x16x32_f16(hfrag[ks], whhN[p][ks], accHN[p], 0,0,0);
      }
    }
    // activations + h update (h old is in registers)
    #pragma unroll
    for (int p = 0; p < 2; p++) {
      const int jl = 32*w + 16*p + n16;
      const float br = sm.brz[jl], bz = sm.brz[128 + jl];
      const float bx = sm.bnx[jl], bn = sm.bnh[jl];
      #pragma unroll
      for (int rg = 0; rg < 4; rg++) {
        const float r  = sigm(accR[p][rg] + br);
        const float z  = sigm(accZ[p][rg] + bz);
        const float nn = tanhfast(accXN[p][rg] + bx + r*(accHN[p][rg] + bn));
        const float ho = hreg[p][rg];
        const float hn = nn + z*(ho - nn);
        hreg[p][rg] = hn;
        sm.hf16[q*4 + rg][jl] = (_Float16)hn;
      }
    }
    __syncthreads();

    // ---- phase CD ----
    #pragma unroll
    for (int ks = 0; ks < 4; ks++)
      hfrag[ks] = *(const half8*)&sm.hf16[n16][ks*32 + q*8];

    const int kk   = (k + 1 < KTOT) ? (k + 1) : (KTOT - 1);
    const int nbuf = (k + 1) & 1;
    if (w == 0) {
      // head -> theta
      f32x4 accH = zero4;
      #pragma unroll
      for (int ks = 0; ks < 4; ks++)
        accH = __builtin_amdgcn_mfma_f32_16x16x32_f16(hfrag[ks], whf[ks], accH, 0,0,0);
      const float bb_ = sm.bhv[n16];
      #pragma unroll
      for (int rg = 0; rg < 4; rg++) {
        const float sg  = sigm(accH[rg] + bb_);
        const float thv = (n16 < 8) ? (0.01f + 2.99f*sg) : (0.3f*sg);
        if (n16 < 13) sm.theta[q*4 + rg][n16] = thv;
      }
      // RK4 (DS ops are in-order per wave: theta writes above land before reads below)
      const float* th = sm.theta[b4];
      const float kfs  = th[s_];
      const float diag = -(kfs + (s_ ? th[3 + s_] : 0.f));
      const float Lc   = s_ ? th[s_ - 1] : 0.f;
      const float Uc   = (s_ < 3) ? th[4 + s_] : 0.f;
      const float U4   = (s_ == 3) ? th[7] : 0.f;
      const float kj   = th[8 + s_];
      const float kf4m = (s_ == 3) ? th[3]  : 0.f;
      const float d4   = (s_ == 3) ? -th[7] : 0.f;
      const float kj5m = (s_ == 3) ? th[12] : 0.f;
      const float uu0 = sm.ust[buf][b4][0], uu1 = sm.ust[buf][b4][1], uu2 = sm.ust[buf][b4][2];
      float y  = sm.yst[b4][s_] + uu0*jr0 + uu1*jr1 + uu2*jr2;
      float y4 = sm.yst[b4][4]  + uu0*j40 + uu1*j41 + uu2*j42;
      const float dt = sm.dtst[buf][b4];
      const float h = dt * 0.1f, hh = 0.5f*h, h6 = h*(1.f/6.f);
      #pragma unroll
      for (int ss = 0; ss < 10; ss++) {
        float yp = dppf<QP_PLUS>(y), ym = dppf<QP_MINUS>(y);
        const float k1  = kj + diag*y + Lc*ym + Uc*yp + U4*y4;
        const float k14 = kj5m + kf4m*y + d4*y4;
        float ty = y + hh*k1, ty4 = y4 + hh*k14;
        yp = dppf<QP_PLUS>(ty); ym = dppf<QP_MINUS>(ty);
        const float k2  = kj + diag*ty + Lc*ym + Uc*yp + U4*ty4;
        const float k24 = kj5m + kf4m*ty + d4*ty4;
        ty = y + hh*k2; ty4 = y4 + hh*k24;
        yp = dppf<QP_PLUS>(ty); ym = dppf<QP_MINUS>(ty);
        const float k3  = kj + diag*ty + Lc*ym + Uc*yp + U4*ty4;
        const float k34 = kj5m + kf4m*ty + d4*ty4;
        ty = y + h*k3; ty4 = y4 + h*k34;
        yp = dppf<QP_PLUS>(ty); ym = dppf<QP_MINUS>(ty);
        const float k4  = kj + diag*ty + Lc*ym + Uc*yp + U4*ty4;
        const float k44 = kj5m + kf4m*ty + d4*ty4;
        y  = fmaxf(y  + h6*(k1  + 2.f*(k2  + k3 ) + k4 ), 0.f);
        y4 = fmaxf(y4 + h6*(k14 + 2.f*(k24 + k34) + k44), 0.f);
      }
      sm.yst[b4][s_] = y;
      if (s_ == 3) sm.yst[b4][4] = y4;
    } else if (w == 1) {
      if (l < 48)
        sm.ust[nbuf][upb][upc] = u_seq[((size_t)(B0 + upb)*KTOT + kk)*3 + upc];
    } else if (w == 2) {
      if (l < 16)
        sm.dtst[nbuf][l] = dt_sq[(size_t)(B0 + l)*KTOT + kk];
    }
    __syncthreads();
  }

  // epilogue: stores for step KTOT-1
  if (t < 80)  yo_base[(size_t)(KTOT-1)*5]  = sm.yst[yb][yi];
  if (t >= 48) th_base[(size_t)(KTOT-1)*13] = sm.theta[tb][tn];
}

extern "C" void kernel_launch(void* const* d_in, const int* in_sizes, int n_in,
                              void* d_out, int out_size, void* d_ws, size_t ws_size,
                              hipStream_t stream) {
  const float* y0     = (const float*)d_in[0];
  const float* u_seq  = (const float*)d_in[1];
  const float* dt_sq  = (const float*)d_in[2];
  const float* Wl     = (const float*)d_in[3];
  const float* bl     = (const float*)d_in[4];
  const float* W_ih   = (const float*)d_in[5];
  const float* b_ih   = (const float*)d_in[6];
  const float* W_hh   = (const float*)d_in[7];
  const float* b_hh   = (const float*)d_in[8];
  const float* Wh     = (const float*)d_in[9];
  const float* bh     = (const float*)d_in[10];
  const float* jmp    = (const float*)d_in[11];
  float* y_out  = (float*)d_out;
  float* th_out = y_out + (size_t)4096 * KTOT * 5;   // y (B,K,5) then theta (B,K,13)
  rnn_scan_kernel<<<256, 256, 0, stream>>>(
      y0, u_seq, dt_sq, Wl, bl, W_ih, b_ih, W_hh, b_hh, Wh, bh, jmp, y_out, th_out);
}

// Round 3
// 1682.876 us; speedup vs baseline: 1.6112x; 1.1292x over previous
//
#include <hip/hip_runtime.h>
#include <cstdint>
#include <cstddef>

// SimpleRNN: B=4096, K=512, U=3, P=5, LIFT=32, HID=128, NSUB=10
// Round 3: exact-linear RK4. RHS is affine (dy = M(theta) y + kj, M tridiagonal,
// theta fixed across the 10 substeps; reference clamps only AFTER each substep).
// So one substep == max(A y + b, 0) with A = I + S Z, b = h S kj,
// Z = hM, S = I + Z/2 + Z^2/6 + Z^3/24  (exact same math, fp-reassociated).
// Build A,b once/step via 3 tridiag x dense 5x5 matmuls (row-per-lane, quad DPP),
// then 10 cheap substeps. u/dt prefetch moved into phase G (drains under G).

#define KTOT 512
#define BB   16

typedef _Float16 half8 __attribute__((ext_vector_type(8)));
typedef float    f32x4 __attribute__((ext_vector_type(4)));

struct __align__(16) Smem {
  _Float16 hf16[BB][136];   // f16 hidden (A-frag source)
  float Wlt[8][32];         // lift weight, transposed
  float bl[32];
  float brz[256];           // b_ih + b_hh for r,z
  float bnx[128];           // b_ih n-gate
  float bnh[128];           // b_hh n-gate
  float bhv[16];
  float theta[BB][14];
  float yst[BB][8];
  float ust[2][BB][4];      // double-buffered u
  float dtst[2][BB];        // double-buffered dt
};

__device__ __forceinline__ float sigm(float x)     { return 1.f / (1.f + __expf(-x)); }
__device__ __forceinline__ float tanhfast(float x) { return 1.f - 2.f / (1.f + __expf(2.f * x)); }

template<int CTRL>
__device__ __forceinline__ float dppf(float x) {
  return __int_as_float(__builtin_amdgcn_mov_dpp(__float_as_int(x), CTRL, 0xf, 0xf, true));
}
#define QP_PLUS  0x39   // quad_perm [1,2,3,0]: lane s <- lane (s+1)&3
#define QP_MINUS 0x93   // quad_perm [3,0,1,2]: lane s <- lane (s-1)&3
#define QB0 0x00        // broadcast lane0 of quad
#define QB1 0x55
#define QB2 0xAA
#define QB3 0xFF

// Y = I + ALPHA * Z * X   (row-per-lane; lane3 also owns row4 in X4r/Y4r).
// Garbage rows off-lane3 in *4 arrays are masked by Zu4==0 / never consumed.
#define MATMUL(Yr, Y4r, Xr, X4r, ALPHA) do {                                  \
  float xm_[5], xp_[5];                                                       \
  _Pragma("unroll")                                                           \
  for (int j_ = 0; j_ < 5; j_++) {                                            \
    xm_[j_] = dppf<QP_MINUS>(Xr[j_]);                                         \
    xp_[j_] = dppf<QP_PLUS >(Xr[j_]);                                         \
  }                                                                           \
  _Pragma("unroll")                                                           \
  for (int j_ = 0; j_ < 5; j_++) {                                            \
    const float ac_ = Zl*xm_[j_] + Zd*Xr[j_] + Zu*xp_[j_] + Zu4*X4r[j_];      \
    const float a4_ = Z43*Xr[j_] + Z44*X4r[j_];                               \
    Yr[j_]  = ((j_ == s_) ? 1.f : 0.f) + (ALPHA)*ac_;                         \
    Y4r[j_] = ((j_ == 4 ) ? 1.f : 0.f) + (ALPHA)*a4_;                         \
  } } while (0)

__global__ __launch_bounds__(256, 1) void rnn_scan_kernel(
    const float* __restrict__ y0,    const float* __restrict__ u_seq,
    const float* __restrict__ dt_sq, const float* __restrict__ Wl,
    const float* __restrict__ bl,    const float* __restrict__ W_ih,
    const float* __restrict__ b_ih,  const float* __restrict__ W_hh,
    const float* __restrict__ b_hh,  const float* __restrict__ Wh,
    const float* __restrict__ bh,    const float* __restrict__ jmp,
    float* __restrict__ y_out, float* __restrict__ th_out)
{
  __shared__ Smem sm;
  const int t   = threadIdx.x;
  const int w   = t >> 6;
  const int l   = t & 63;
  const int n16 = l & 15;
  const int q   = l >> 4;
  const int B0  = blockIdx.x * BB;

  // ---------------- one-time init ----------------
  for (int i = t; i < 32*8; i += 256) { const int oo = i >> 3, c = i & 7;
    sm.Wlt[c][oo] = Wl[i]; }
  if (t < 32)  sm.bl[t] = bl[t];
  sm.brz[t] = b_ih[t] + b_hh[t];
  if (t < 128) { sm.bnx[t] = b_ih[256+t]; sm.bnh[t] = b_hh[256+t]; }
  if (t < 16)  sm.bhv[t] = (t < 13) ? bh[t] : 0.f;
  if (t < 128) { const int b = t >> 3, i = t & 7;
    sm.yst[b][i] = (i < 5) ? (y0[(size_t)(B0+b)*5 + i] + 0.01f) : 0.f; }
  if (t < 48) { const int b = t/3, c = t - b*3;
    sm.ust[0][b][c] = u_seq[((size_t)(B0+b)*KTOT + 0)*3 + c]; }
  if (t >= 48 && t < 64) sm.dtst[0][t-48] = dt_sq[(size_t)(B0+(t-48))*KTOT + 0];

  // head B-frags in registers (wave0 use)
  half8 whf[4];
  #pragma unroll
  for (int ks = 0; ks < 4; ks++)
    #pragma unroll
    for (int i = 0; i < 8; i++) {
      const int kk = ks*32 + q*8 + i;
      whf[ks][i] = (n16 < 13) ? (_Float16)Wh[n16*128 + kk] : (_Float16)0.f;
    }

  // GRU weight fragments
  half8 wihR[2], wihZ[2], wihN[2], whhR[2][4], whhZ[2][4], whhN[2][4];
  #pragma unroll
  for (int p = 0; p < 2; p++) {
    const int jR = (2*w + p)*16 + n16;
    const int jZ = jR + 128, jN = jR + 256;
    #pragma unroll
    for (int i = 0; i < 8; i++) {
      const int kk = q*8 + i;
      wihR[p][i] = (_Float16)W_ih[jR*32 + kk];
      wihZ[p][i] = (_Float16)W_ih[jZ*32 + kk];
      wihN[p][i] = (_Float16)W_ih[jN*32 + kk];
    }
    #pragma unroll
    for (int ks = 0; ks < 4; ks++)
      #pragma unroll
      for (int i = 0; i < 8; i++) {
        const int kk = ks*32 + q*8 + i;
        whhR[p][ks][i] = (_Float16)W_hh[jR*128 + kk];
        whhZ[p][ks][i] = (_Float16)W_hh[jZ*128 + kk];
        whhN[p][ks][i] = (_Float16)W_hh[jN*128 + kk];
      }
  }

  float hreg[2][4];
  #pragma unroll
  for (int p = 0; p < 2; p++)
    #pragma unroll
    for (int rg = 0; rg < 4; rg++) hreg[p][rg] = 0.f;
  half8 hfrag[4];
  #pragma unroll
  for (int ks = 0; ks < 4; ks++)
    #pragma unroll
    for (int i = 0; i < 8; i++) hfrag[ks][i] = (_Float16)0.f;

  // RK4 lane mapping (wave0): lane = b4*4 + s_, row4 state on s_==3
  const int s_ = l & 3, b4 = l >> 2;
  const float jr0 = jmp[0*5 + s_], jr1 = jmp[1*5 + s_], jr2 = jmp[2*5 + s_];
  const float j40 = (s_==3) ? jmp[4]  : 0.f;
  const float j41 = (s_==3) ? jmp[9]  : 0.f;
  const float j42 = (s_==3) ? jmp[14] : 0.f;

  // output store mapping
  const int yb = t/5, yi = t - yb*5;                 // t<80
  float* yo_base = y_out + ((size_t)(B0 + (yb & 15))*KTOT)*5 + yi;
  const int ts = (t >= 48) ? (t - 48) : 0;           // t in [48,256)
  const int tb = ts/13, tn = ts - tb*13;
  float* th_base = th_out + ((size_t)(B0 + tb)*KTOT)*13 + tn;
  // u-prefetch mapping (wave1)
  const int upb = l/3, upc = l - upb*3;              // l<48

  __syncthreads();

  const f32x4 zero4 = {0.f, 0.f, 0.f, 0.f};

  #pragma unroll 1
  for (int k = 0; k < KTOT; k++) {
    const int buf  = k & 1;
    const int nbuf = (k + 1) & 1;
    const int kp   = (k + 1 < KTOT) ? (k + 1) : (KTOT - 1);

    // ---- phase G ----
    // issue global traffic first: output stores of step k-1 + prefetch of step k+1
    float pref_u = 0.f, pref_dt = 0.f;
    if (w == 1 && l < 48)
      pref_u = u_seq[((size_t)(B0 + upb)*KTOT + kp)*3 + upc];
    if (w == 2 && l < 16)
      pref_dt = dt_sq[(size_t)(B0 + l)*KTOT + kp];
    if (k > 0) {
      if (t < 80)  yo_base[(size_t)(k-1)*5]  = sm.yst[yb][yi];
      if (t >= 48) th_base[(size_t)(k-1)*13] = sm.theta[tb][tn];
    }
    // per-lane redundant lift -> A-frag
    const float u0 = sm.ust[buf][n16][0], u1 = sm.ust[buf][n16][1], u2 = sm.ust[buf][n16][2];
    const float ya = sm.yst[n16][0], yB = sm.yst[n16][1], yc = sm.yst[n16][2],
                yd = sm.yst[n16][3], ye = sm.yst[n16][4];
    half8 xf;
    #pragma unroll
    for (int i = 0; i < 8; i++) {
      const int oo = q*8 + i;
      const float a = sm.bl[oo]
        + u0*sm.Wlt[0][oo] + u1*sm.Wlt[1][oo] + u2*sm.Wlt[2][oo]
        + ya*sm.Wlt[3][oo] + yB*sm.Wlt[4][oo] + yc*sm.Wlt[5][oo]
        + yd*sm.Wlt[6][oo] + ye*sm.Wlt[7][oo];
      xf[i] = (_Float16)(a * sigm(a));
    }
    // gates
    f32x4 accR[2], accZ[2], accXN[2], accHN[2];
    #pragma unroll
    for (int p = 0; p < 2; p++) {
      accR[p]  = __builtin_amdgcn_mfma_f32_16x16x32_f16(xf, wihR[p], zero4, 0,0,0);
      accZ[p]  = __builtin_amdgcn_mfma_f32_16x16x32_f16(xf, wihZ[p], zero4, 0,0,0);
      accXN[p] = __builtin_amdgcn_mfma_f32_16x16x32_f16(xf, wihN[p], zero4, 0,0,0);
      accHN[p] = zero4;
      #pragma unroll
      for (int ks = 0; ks < 4; ks++) {
        accR[p]  = __builtin_amdgcn_mfma_f32_16x16x32_f16(hfrag[ks], whhR[p][ks], accR[p], 0,0,0);
        accZ[p]  = __builtin_amdgcn_mfma_f32_16x16x32_f16(hfrag[ks], whhZ[p][ks], accZ[p], 0,0,0);
        accHN[p] = __builtin_amdgcn_mfma_f32_16x16x32_f16(hfrag[ks], whhN[p][ks], accHN[p], 0,0,0);
      }
    }
    // activations + h update
    #pragma unroll
    for (int p = 0; p < 2; p++) {
      const int jl = 32*w + 16*p + n16;
      const float br = sm.brz[jl], bz = sm.brz[128 + jl];
      const float bx = sm.bnx[jl], bn = sm.bnh[jl];
      #pragma unroll
      for (int rg = 0; rg < 4; rg++) {
        const float r  = sigm(accR[p][rg] + br);
        const float z  = sigm(accZ[p][rg] + bz);
        const float nn = tanhfast(accXN[p][rg] + bx + r*(accHN[p][rg] + bn));
        const float ho = hreg[p][rg];
        const float hn = nn + z*(ho - nn);
        hreg[p][rg] = hn;
        sm.hf16[q*4 + rg][jl] = (_Float16)hn;
      }
    }
    // land prefetch into LDS (loads have had the whole phase to complete)
    if (w == 1 && l < 48) sm.ust[nbuf][upb][upc] = pref_u;
    if (w == 2 && l < 16) sm.dtst[nbuf][l] = pref_dt;
    __syncthreads();

    // ---- phase CD ----
    #pragma unroll
    for (int ks = 0; ks < 4; ks++)
      hfrag[ks] = *(const half8*)&sm.hf16[n16][ks*32 + q*8];

    if (w == 0) {
      // head -> theta
      f32x4 accH = zero4;
      #pragma unroll
      for (int ks = 0; ks < 4; ks++)
        accH = __builtin_amdgcn_mfma_f32_16x16x32_f16(hfrag[ks], whf[ks], accH, 0,0,0);
      const float bb_ = sm.bhv[n16];
      #pragma unroll
      for (int rg = 0; rg < 4; rg++) {
        const float sg  = sigm(accH[rg] + bb_);
        const float thv = (n16 < 8) ? (0.01f + 2.99f*sg) : (0.3f*sg);
        if (n16 < 13) sm.theta[q*4 + rg][n16] = thv;
      }
      // ---- exact-linear RK4 (ds ops in-order within wave: theta writes land first) ----
      const float* th = sm.theta[b4];
      const float dt = sm.dtst[buf][b4];
      const float h  = dt * 0.1f;
      // Z = h*M coefficients for this lane's row s_ (and row4, all lanes compute)
      const float thm = th[s_ ? (s_ - 1) : 0];
      const float Zl  = s_ ? h*thm : 0.f;            // Z[s][s-1]
      const float krs = s_ ? th[3 + s_] : 0.f;
      const float Zd  = -h*(th[s_] + krs);           // Z[s][s]
      const float Zur = h*th[4 + s_];                // true super-diag (s=3 -> Z[3][4])
      const float Zu  = (s_ < 3) ? Zur : 0.f;
      const float Zu4 = (s_ == 3) ? Zur : 0.f;
      const float Z43 = h*th[3];                     // Z[4][3]
      const float Z44 = -h*th[7];                    // Z[4][4]
      const float c0 = th[8], c1 = th[9], c2 = th[10], c3 = th[11], c4 = th[12];
      // X1 = I + Z/4 (hand init)
      float Xa[5], Xa4[5], Xb[5], Xb4[5];
      #pragma unroll
      for (int j = 0; j < 5; j++) {
        const float zr = (j == s_) ? Zd : ((j == s_ + 1) ? Zur : ((j + 1 == s_) ? Zl : 0.f));
        Xa[j] = ((j == s_) ? 1.f : 0.f) + 0.25f*zr;
      }
      Xa4[0] = 0.f; Xa4[1] = 0.f; Xa4[2] = 0.f;
      Xa4[3] = 0.25f*Z43; Xa4[4] = 1.f + 0.25f*Z44;
      MATMUL(Xb, Xb4, Xa, Xa4, (1.f/3.f));   // X2 = I + (Z/3) X1
      MATMUL(Xa, Xa4, Xb, Xb4, 0.5f);        // X3 = S = I + (Z/2) X2
      const float bv  = h*(Xa[0]*c0 + Xa[1]*c1 + Xa[2]*c2 + Xa[3]*c3 + Xa[4]*c4);
      const float bv4 = h*(Xa4[0]*c0 + Xa4[1]*c1 + Xa4[2]*c2 + Xa4[3]*c3 + Xa4[4]*c4);
      MATMUL(Xb, Xb4, Xa, Xa4, 1.f);         // A = I + Z S
      // y init with bolus jump
      const float uu0 = sm.ust[buf][b4][0], uu1 = sm.ust[buf][b4][1], uu2 = sm.ust[buf][b4][2];
      float y  = sm.yst[b4][s_] + uu0*jr0 + uu1*jr1 + uu2*jr2;
      float y4 = sm.yst[b4][4]  + uu0*j40 + uu1*j41 + uu2*j42;
      // 10 substeps: y+ = max(A y + b, 0)   (exactly reference RK4 substep)
      #pragma unroll
      for (int ss = 0; ss < 10; ss++) {
        const float v0 = dppf<QB0>(y), v1 = dppf<QB1>(y),
                    v2 = dppf<QB2>(y), v3 = dppf<QB3>(y);
        const float v4 = dppf<QB3>(y4);
        const float yn  = fmaxf(bv  + Xb[0]*v0 + Xb[1]*v1 + Xb[2]*v2 + Xb[3]*v3 + Xb[4]*v4, 0.f);
        const float y4n = fmaxf(bv4 + Xb4[0]*v0 + Xb4[1]*v1 + Xb4[2]*v2 + Xb4[3]*v3 + Xb4[4]*v4, 0.f);
        y = yn; y4 = y4n;
      }
      sm.yst[b4][s_] = y;
      if (s_ == 3) sm.yst[b4][4] = y4;
    }
    __syncthreads();
  }

  // epilogue: stores for step KTOT-1
  if (t < 80)  yo_base[(size_t)(KTOT-1)*5]  = sm.yst[yb][yi];
  if (t >= 48) th_base[(size_t)(KTOT-1)*13] = sm.theta[tb][tn];
}

extern "C" void kernel_launch(void* const* d_in, const int* in_sizes, int n_in,
                              void* d_out, int out_size, void* d_ws, size_t ws_size,
                              hipStream_t stream) {
  const float* y0     = (const float*)d_in[0];
  const float* u_seq  = (const float*)d_in[1];
  const float* dt_sq  = (const float*)d_in[2];
  const float* Wl     = (const float*)d_in[3];
  const float* bl     = (const float*)d_in[4];
  const float* W_ih   = (const float*)d_in[5];
  const float* b_ih   = (const float*)d_in[6];
  const float* W_hh   = (const float*)d_in[7];
  const float* b_hh   = (const float*)d_in[8];
  const float* Wh     = (const float*)d_in[9];
  const float* bh     = (const float*)d_in[10];
  const float* jmp    = (const float*)d_in[11];
  float* y_out  = (float*)d_out;
  float* th_out = y_out + (size_t)4096 * KTOT * 5;   // y (B,K,5) then theta (B,K,13)
  rnn_scan_kernel<<<256, 256, 0, stream>>>(
      y0, u_seq, dt_sq, Wl, bl, W_ih, b_ih, W_hh, b_hh, Wh, bh, jmp, y_out, th_out);
}